// Round 10
// baseline (198.660 us; speedup 1.0000x reference)
//
#include <hip/hip_runtime.h>
#include <math.h>

#define Bb 256
#define Tt 256
#define Ee 384
#define Hh 64

typedef __attribute__((ext_vector_type(8))) short bf16x8;
typedef __attribute__((ext_vector_type(4))) float f32x4;
typedef __attribute__((ext_vector_type(4))) unsigned int u32x4;

__device__ inline short f2bf(float f) {
    unsigned u = __float_as_uint(f);
    u += 0x7FFFu + ((u >> 16) & 1);      // RNE
    return (short)(u >> 16);
}
__device__ inline float bf2f(short s) {
    return __uint_as_float(((unsigned)(unsigned short)s) << 16);
}
// packed f32x2 -> bf16x2 (RNE). D[15:0]=bf16(a), D[31:16]=bf16(b)
__device__ inline unsigned cvt_pk_bf16(float a, float b) {
    unsigned r;
    asm("v_cvt_pk_bf16_f32 %0, %1, %2" : "=v"(r) : "v"(a), "v"(b));
    return r;
}
__device__ inline float lo16f(unsigned u) { return __uint_as_float(u << 16); }
__device__ inline float hi16f(unsigned u) { return __uint_as_float(u & 0xFFFF0000u); }

#define MFMA16(a, b, c) __builtin_amdgcn_mfma_f32_16x16x32_bf16((a), (b), (c), 0, 0, 0)

// ---- W fragment buffer in d_ws: hi at 0, lo at 147456; frag (ec*12+tct)*1024 ----
#define WLO_OFF 147456

// ---- LDS byte offsets ----
// phase 1: A dbuf at p*32768 (hi) / +16384 (lo); B dbuf at 65536 + p*24576 (hi) / +12288 (lo)
// raw-x DMA ring slot (one ec slice, chunk-major [c][row]) at 114688 (32 KB)
#define BB0 65536
#define RAW 114688
// phase 2 (live after phase 1; RAW is dead by then):
#define K_HI 0
#define K_LO 32768
#define VF   65536
#define QH   98304
#define QL   116736
#define PBASE 98304
#define SMEM_BYTES 147456

// ============ prep kernel: W -> bf16 hi/lo in B-fragment layout (coalesced) ============
__global__ __launch_bounds__(256) void prep_w(
    const float* __restrict__ Wq, const float* __restrict__ Wk,
    const float* __restrict__ Wv, unsigned char* __restrict__ wsp)
{
    __shared__ float wlds[32 * 66];
    const int bid = blockIdx.x;                // 0..35
    const int ec  = bid / 3, m = bid - ec * 3;
    const float* Wm = (m == 0) ? Wq : (m == 1 ? Wk : Wv);
    const int tid = threadIdx.x;

    const float4* src = reinterpret_cast<const float4*>(Wm + ec * 2048) + tid * 2;
    float4 a = src[0], b = src[1];
    int f = tid * 8;
    float* d = wlds + (f >> 6) * 66 + (f & 63);
    d[0] = a.x; d[1] = a.y; d[2] = a.z; d[3] = a.w;
    d[4] = b.x; d[5] = b.y; d[6] = b.z; d[7] = b.w;
    __syncthreads();

    const int tl = tid >> 6, lu = tid & 63;
    const int koct = lu >> 4, n = lu & 15;
    const int c = tl * 16 + n;
    bf16x8 hi8, lo8;
    #pragma unroll
    for (int j = 0; j < 8; ++j) {
        float v = wlds[(koct * 8 + j) * 66 + c];
        short h = f2bf(v);
        hi8[j] = h;
        lo8[j] = f2bf(v - bf2f(h));
    }
    const int frag = ec * 12 + m * 4 + tl;
    *reinterpret_cast<bf16x8*>(wsp + frag * 1024 + lu * 16) = hi8;
    *reinterpret_cast<bf16x8*>(wsp + WLO_OFF + frag * 1024 + lu * 16) = lo8;
}

// ============ main fused kernel: producer/consumer phase-1 with raw-x DMA pipeline ============
// waves 0-11: consumers. rg=w&3 -> rowtiles 4rg..4rg+3; cg=w>>2 -> coltiles 4cg..4cg+3.
// waves 12-15: producers. Per ec: read raw(ec+1) from LDS -> issue B-DMA(ec+1) ->
//   issue raw-DMA(ec+2) -> convert+write A(ec+1) -> vmcnt(8) (raw DMA survives barrier).
// Phase-1 barriers are raw s_barrier (no vmcnt(0) drain) + explicit counted waits.
// REGISTER BUDGET NOTE: 16 waves/CU caps unified VGPR+AGPR at 128/wave; acc[4][4]
// is 64 AGPR + 64 VGPR = full. NO loop-carried registers in phase 1 (R8 lesson:
// px[8] held across the loop -> 257 MB scratch spill, 2.3x regression). The raw-x
// pipeline lives in LDS, not registers.
__global__ __launch_bounds__(1024) void head_fused(
    const float* __restrict__ x,
    const float* __restrict__ bq, const float* __restrict__ bk,
    const float* __restrict__ bv,
    const unsigned char* __restrict__ wsp,
    float* __restrict__ out)
{
    __shared__ __align__(16) unsigned char smem[SMEM_BYTES];

    const int b    = blockIdx.x;
    const int tid  = threadIdx.x;
    const int w    = tid >> 6;        // wave 0..15
    const int lane = tid & 63;
    const int quad = lane >> 4;
    const int nl   = lane & 15;
    const bool producer = (w >= 12);
    const int rg   = w & 3;           // consumer rowgroup
    const int cg   = w >> 2;          // consumer colgroup (0..2)

    f32x4 acc[4][4];
    #pragma unroll
    for (int i = 0; i < 4; ++i)
        #pragma unroll
        for (int j = 0; j < 4; ++j) acc[i][j] = (f32x4){0,0,0,0};

    const float4* x4 = reinterpret_cast<const float4*>(x + (size_t)b * Tt * Ee);

    // producer-issued B-frag DMA: producer (w-12) moves frag-pairs 3(w-12)..+2 (6 inst)
    auto bgld = [&](int ecn) {
        int p = ecn & 1;
        int f0 = (w - 12) * 3;
        #pragma unroll
        for (int j = 0; j < 3; ++j) {
            const unsigned char* g = wsp + (size_t)(ecn * 12 + f0 + j) * 1024 + (size_t)lane * 16;
            unsigned char* dlds = smem + BB0 + p * 24576 + (f0 + j) * 1024;
            __builtin_amdgcn_global_load_lds(
                (const __attribute__((address_space(1))) unsigned*)g,
                (__attribute__((address_space(3))) unsigned*)dlds, 16, 0, 0);
            __builtin_amdgcn_global_load_lds(
                (const __attribute__((address_space(1))) unsigned*)(g + WLO_OFF),
                (__attribute__((address_space(3))) unsigned*)(dlds + 12288), 16, 0, 0);
        }
    };

    // raw-x DMA (producers, 8 inst): slice ecsrc -> RAW, chunk-major layout
    // [c][row]: LDS addr = RAW + c*4096 + row*16. Wave (w-12) covers its own rows
    // wr0..wr0+63; inst c writes 1 KB contiguous at RAW + c*4096 + wr0*16 (HW: +lane*16
    // = row wr0+lane). Global src lane: row wr0+lane, floats 4c..4c+3.
    const int pt = tid & 255;                     // producer row (= wr0 + lane)
    const float4* xp = x4 + pt * 96;
    unsigned char* adst = smem + (pt >> 4) * 1024 + (pt & 15) * 16;

    auto rawdma = [&](int ecsrc) {
        unsigned char* rbase = smem + RAW + (w - 12) * 1024;
        #pragma unroll
        for (int c = 0; c < 8; ++c) {
            __builtin_amdgcn_global_load_lds(
                (const __attribute__((address_space(1))) unsigned*)(xp + ecsrc * 8 + c),
                (__attribute__((address_space(3))) unsigned*)(rbase + c * 4096),
                16, 0, 0);
        }
    };

    // convert px -> hi/lo A fragments (transient registers only)
    auto stageWrite = [&](int nb, const float4* px) {
        #pragma unroll
        for (int ko = 0; ko < 4; ++ko) {
            float v0 = px[2*ko+0].x, v1 = px[2*ko+0].y,
                  v2 = px[2*ko+0].z, v3 = px[2*ko+0].w,
                  v4 = px[2*ko+1].x, v5 = px[2*ko+1].y,
                  v6 = px[2*ko+1].z, v7 = px[2*ko+1].w;
            unsigned h0 = cvt_pk_bf16(v0, v1);
            unsigned h1 = cvt_pk_bf16(v2, v3);
            unsigned h2 = cvt_pk_bf16(v4, v5);
            unsigned h3 = cvt_pk_bf16(v6, v7);
            unsigned l0 = cvt_pk_bf16(v0 - lo16f(h0), v1 - hi16f(h0));
            unsigned l1 = cvt_pk_bf16(v2 - lo16f(h1), v3 - hi16f(h1));
            unsigned l2 = cvt_pk_bf16(v4 - lo16f(h2), v5 - hi16f(h2));
            unsigned l3 = cvt_pk_bf16(v6 - lo16f(h3), v7 - hi16f(h3));
            u32x4 hv = {h0, h1, h2, h3};
            u32x4 lv = {l0, l1, l2, l3};
            *reinterpret_cast<u32x4*>(adst + nb + ko * 256) = hv;
            *reinterpret_cast<u32x4*>(adst + nb + 16384 + ko * 256) = lv;
        }
    };

    // read raw slice (resident in RAW) into transient regs; conflict-free lane*16 pattern
    auto readRaw = [&](float4* px) {
        #pragma unroll
        for (int j = 0; j < 8; ++j)
            px[j] = *reinterpret_cast<float4*>(smem + RAW + j * 4096 + pt * 16);
    };

    // ---- preloop (producers): raw(0) -> A(0); leave raw(1) + nothing else in flight ----
    if (producer) {
        rawdma(0);                                        // 8 in flight
        asm volatile("s_waitcnt vmcnt(0)" ::: "memory");  // raw(0) resident
        float4 px[8];
        readRaw(px);
        asm volatile("s_waitcnt lgkmcnt(0)" ::: "memory");
        __builtin_amdgcn_sched_barrier(0);                // raw reads done before overwrite
        bgld(0);                                          // 6 in flight (oldest)
        rawdma(1);                                        // +8 (youngest)
        stageWrite(0, px);                                // A(0) -> buffer 0
        asm volatile("s_waitcnt vmcnt(8) lgkmcnt(0)" ::: "memory"); // drain B(0); raw(1) flies
    }

    // ================= Phase 1: raw s_barrier per ec; counted vmcnt =================
    for (int ec = 0; ec < 12; ++ec) {
        __builtin_amdgcn_s_barrier();        // A(ec)+B(ec) published by producer waits
        asm volatile("" ::: "memory");       // no memory-op motion across the barrier
        if (producer) {
            if (ec < 11) {
                asm volatile("s_waitcnt vmcnt(0)" ::: "memory");  // raw(ec+1) resident
                float4 px[8];
                readRaw(px);
                asm volatile("s_waitcnt lgkmcnt(0)" ::: "memory");
                __builtin_amdgcn_sched_barrier(0);                // reads before overwrite
                bgld(ec + 1);                                     // 6 (oldest)
                if (ec < 10) rawdma(ec + 2);                      // +8 (youngest)
                stageWrite((1 - (ec & 1)) * 32768, px);           // A(ec+1)
                if (ec < 10)
                    asm volatile("s_waitcnt vmcnt(8) lgkmcnt(0)" ::: "memory");
                else
                    asm volatile("s_waitcnt vmcnt(0) lgkmcnt(0)" ::: "memory");
            }
        } else {
            const int ab = (ec & 1) * 32768;
            const int bb = BB0 + (ec & 1) * 24576;
            bf16x8 bh[4], bl[4];
            #pragma unroll
            for (int ct = 0; ct < 4; ++ct) {
                int o = bb + (cg * 4 + ct) * 1024 + lane * 16;
                bh[ct] = *reinterpret_cast<bf16x8*>(smem + o);
                bl[ct] = *reinterpret_cast<bf16x8*>(smem + o + 12288);
            }
            __builtin_amdgcn_s_setprio(1);
            #pragma unroll
            for (int rt = 0; rt < 4; ++rt) {
                int ao = ab + (rg * 4 + rt) * 1024 + lane * 16;
                bf16x8 ah = *reinterpret_cast<bf16x8*>(smem + ao);
                bf16x8 al = *reinterpret_cast<bf16x8*>(smem + ao + 16384);
                #pragma unroll
                for (int ct = 0; ct < 4; ++ct) {
                    acc[rt][ct] = MFMA16(ah, bh[ct], acc[rt][ct]);
                    acc[rt][ct] = MFMA16(al, bh[ct], acc[rt][ct]);
                    acc[rt][ct] = MFMA16(ah, bl[ct], acc[rt][ct]);
                }
            }
            __builtin_amdgcn_s_setprio(0);
        }
    }
    __syncthreads();   // full drain; staging + RAW dead; phase-2 regions go live

    // ---- bias fold + K/V scatter (consumers; cg-uniform) ----
    if (!producer) {
        const float* bias_m = (cg == 0) ? bq : (cg == 1 ? bk : bv);
        #pragma unroll
        for (int ct = 0; ct < 4; ++ct) {
            float bias = bias_m[ct * 16 + nl];
            #pragma unroll
            for (int rt = 0; rt < 4; ++rt)
                #pragma unroll
                for (int r = 0; r < 4; ++r) acc[rt][ct][r] += bias;
        }

        if (cg == 1) {
            // K scatter (hi/lo), h = ct*16+nl, s = rg*64+rt*16+quad*4+r; r -> +16B
            #pragma unroll
            for (int ct = 0; ct < 4; ++ct) {
                int h = ct * 16 + nl;
                #pragma unroll
                for (int rt = 0; rt < 4; ++rt) {
                    f32x4 v = acc[rt][ct];
                    unsigned h01 = cvt_pk_bf16(v[0], v[1]);
                    unsigned h23 = cvt_pk_bf16(v[2], v[3]);
                    unsigned l01 = cvt_pk_bf16(v[0] - lo16f(h01), v[1] - hi16f(h01));
                    unsigned l23 = cvt_pk_bf16(v[2] - lo16f(h23), v[3] - hi16f(h23));
                    int a0 = ((rg * 4 + rt) * 2 + (h >> 5)) * 1024
                           + ((((h & 31) >> 3) * 16 + quad * 4) * 8 + (h & 7)) * 2;
                    *reinterpret_cast<short*>(smem + K_HI + a0)      = (short)h01;
                    *reinterpret_cast<short*>(smem + K_HI + a0 + 16) = (short)(h01 >> 16);
                    *reinterpret_cast<short*>(smem + K_HI + a0 + 32) = (short)h23;
                    *reinterpret_cast<short*>(smem + K_HI + a0 + 48) = (short)(h23 >> 16);
                    *reinterpret_cast<short*>(smem + K_LO + a0)      = (short)l01;
                    *reinterpret_cast<short*>(smem + K_LO + a0 + 16) = (short)(l01 >> 16);
                    *reinterpret_cast<short*>(smem + K_LO + a0 + 32) = (short)l23;
                    *reinterpret_cast<short*>(smem + K_LO + a0 + 48) = (short)(l23 >> 16);
                }
            }
        } else if (cg == 2) {
            // V scatter (bf16): consecutive r are contiguous shorts -> 2x b32 store
            #pragma unroll
            for (int ct = 0; ct < 4; ++ct) {
                int h = ct * 16 + nl;
                #pragma unroll
                for (int rt = 0; rt < 4; ++rt) {
                    f32x4 v = acc[rt][ct];
                    unsigned h01 = cvt_pk_bf16(v[0], v[1]);
                    unsigned h23 = cvt_pk_bf16(v[2], v[3]);
                    int s29 = rg * 2 + (rt >> 1);                  // s>>5
                    int slh = (rt & 1) * 2 + (quad >> 1);          // sl>>3
                    int sl7 = (quad & 1) * 4;                      // sl&7 (r=0)
                    int a0 = (s29 * 4 + (h >> 4)) * 1024
                           + ((slh * 16 + (h & 15)) * 8 + sl7) * 2;
                    *reinterpret_cast<unsigned*>(smem + VF + a0)     = h01;
                    *reinterpret_cast<unsigned*>(smem + VF + a0 + 4) = h23;
                }
            }
        }
    }

    // ---- Q round-trip through LDS, two half-phases (cg==0 waves write) ----
    auto writeQhalf = [&]() {
        #pragma unroll
        for (int ct = 0; ct < 4; ++ct) {
            int col = ct * 16 + nl;
            #pragma unroll
            for (int rt = 0; rt < 4; ++rt) {
                f32x4 v = acc[rt][ct];
                unsigned h01 = cvt_pk_bf16(v[0], v[1]);
                unsigned h23 = cvt_pk_bf16(v[2], v[3]);
                unsigned l01 = cvt_pk_bf16(v[0] - lo16f(h01), v[1] - hi16f(h01));
                unsigned l23 = cvt_pk_bf16(v[2] - lo16f(h23), v[3] - hi16f(h23));
                int s0 = rg * 64 + rt * 16 + quad * 4;
                int a0 = ((s0 & 127) * 72 + col) * 2;              // r -> +144B
                *reinterpret_cast<short*>(smem + QH + a0)       = (short)h01;
                *reinterpret_cast<short*>(smem + QH + a0 + 144) = (short)(h01 >> 16);
                *reinterpret_cast<short*>(smem + QH + a0 + 288) = (short)h23;
                *reinterpret_cast<short*>(smem + QH + a0 + 432) = (short)(h23 >> 16);
                *reinterpret_cast<short*>(smem + QL + a0)       = (short)l01;
                *reinterpret_cast<short*>(smem + QL + a0 + 144) = (short)(l01 >> 16);
                *reinterpret_cast<short*>(smem + QL + a0 + 288) = (short)l23;
                *reinterpret_cast<short*>(smem + QL + a0 + 432) = (short)(l23 >> 16);
            }
        }
    };
    bf16x8 qh0, qh1, ql0, ql1;
    auto readQ = [&]() {
        int rloc = (16 * w + nl) & 127;
        int base = rloc * 144;
        qh0 = *reinterpret_cast<bf16x8*>(smem + QH + base + quad * 16);
        qh1 = *reinterpret_cast<bf16x8*>(smem + QH + base + 64 + quad * 16);
        ql0 = *reinterpret_cast<bf16x8*>(smem + QL + base + quad * 16);
        ql1 = *reinterpret_cast<bf16x8*>(smem + QL + base + 64 + quad * 16);
    };

    if (!producer && cg == 0 && rg < 2) writeQhalf();   // rows 0..127
    __syncthreads();
    if (w < 8) readQ();
    __syncthreads();
    if (!producer && cg == 0 && rg >= 2) writeQhalf();  // rows 128..255
    __syncthreads();
    if (w >= 8) readQ();
    __syncthreads();

    // ================= Phase 2: causal attention, wave w owns rows 16w..16w+15 =================
    f32x4 oacc[4];
    #pragma unroll
    for (int i = 0; i < 4; ++i) oacc[i] = (f32x4){0,0,0,0};
    float lsum = 0.f;
    const int t0 = w * 16;
    unsigned char* pb = smem + PBASE + w * 1344;
    const int npairs = (w >> 1) + 1;

    for (int p = 0; p < npairs; ++p) {
        #pragma unroll
        for (int hf = 0; hf < 2; ++hf) {
            int st = 2 * p + hf;
            f32x4 s0 = (f32x4){0,0,0,0}, s1 = (f32x4){0,0,0,0};
            int kb = st * 2048 + lane * 16;
            bf16x8 kh0 = *reinterpret_cast<bf16x8*>(smem + K_HI + kb);
            bf16x8 kh1 = *reinterpret_cast<bf16x8*>(smem + K_HI + kb + 1024);
            bf16x8 kl0 = *reinterpret_cast<bf16x8*>(smem + K_LO + kb);
            bf16x8 kl1 = *reinterpret_cast<bf16x8*>(smem + K_LO + kb + 1024);
            s0 = MFMA16(qh0, kh0, s0);
            s1 = MFMA16(qh1, kh1, s1);
            s0 = MFMA16(ql0, kh0, s0);
            s1 = MFMA16(ql1, kh1, s1);
            s0 = MFMA16(qh0, kl0, s0);
            s1 = MFMA16(qh1, kl1, s1);
            int sg = st * 16 + nl;
            #pragma unroll
            for (int r = 0; r < 4; ++r) {
                int tg = t0 + quad * 4 + r;
                float sv = s0[r] + s1[r];
                float pv = (sg <= tg) ? __expf(sv) : 0.f;
                *reinterpret_cast<short*>(pb + ((quad * 4 + r) * 40 + hf * 16 + nl) * 2) = f2bf(pv);
            }
        }
        asm volatile("s_waitcnt lgkmcnt(0)" ::: "memory");
        bf16x8 pa = *reinterpret_cast<bf16x8*>(pb + (nl * 40 + quad * 8) * 2);
        float ls = 0.f;
        #pragma unroll
        for (int j = 0; j < 8; ++j) ls += bf2f(pa[j]);
        ls += __shfl_xor(ls, 16);
        ls += __shfl_xor(ls, 32);
        lsum += ls;
        int vb = p * 4096 + lane * 16;
        #pragma unroll
        for (int nt = 0; nt < 4; ++nt) {
            bf16x8 vf = *reinterpret_cast<bf16x8*>(smem + VF + vb + nt * 1024);
            oacc[nt] = MFMA16(pa, vf, oacc[nt]);
        }
    }

    // ---- normalize + write out ----
    float* lb_ = reinterpret_cast<float*>(pb + 1280);
    if (lane < 16) lb_[lane] = lsum;
    asm volatile("s_waitcnt lgkmcnt(0)" ::: "memory");
    float* ob = out + (size_t)b * Tt * Hh + (size_t)t0 * Hh;
    #pragma unroll
    for (int r = 0; r < 4; ++r) {
        float inv = 1.0f / lb_[quad * 4 + r];
        #pragma unroll
        for (int nt = 0; nt < 4; ++nt)
            ob[(quad * 4 + r) * 64 + nt * 16 + nl] = oacc[nt][r] * inv;
    }
}

extern "C" void kernel_launch(void* const* d_in, const int* in_sizes, int n_in,
                              void* d_out, int out_size, void* d_ws, size_t ws_size,
                              hipStream_t stream) {
    const float* x  = (const float*)d_in[0];
    const float* Wq = (const float*)d_in[1];
    const float* bq = (const float*)d_in[2];
    const float* Wk = (const float*)d_in[3];
    const float* bk = (const float*)d_in[4];
    const float* Wv = (const float*)d_in[5];
    const float* bv = (const float*)d_in[6];
    float* out = (float*)d_out;
    unsigned char* wsp = (unsigned char*)d_ws;   // needs 294912 B
    hipLaunchKernelGGL(prep_w, dim3(36), dim3(256), 0, stream, Wq, Wk, Wv, wsp);
    hipLaunchKernelGGL(head_fused, dim3(Bb), dim3(1024), 0, stream,
                       x, bq, bk, bv, wsp, out);
}